// Round 8
// baseline (67.624 us; speedup 1.0000x reference)
//
#include <hip/hip_runtime.h>
#include <math.h>

#define DIM 256
#define RPW 32   // rows per wave

// ---------------------------------------------------------------------------
// K0 setup (4 blocks, one per output qubit q): builds M[q] = T[q] reshaped as
// 16x16 over (j=p0*4+p1, k=p2*4+p3) in d_ws. Validated math from round 2.
// z_q(row) = sum_{j,k} u_j M[q][j][k] v_k,  u = a0(x)a1, v = a2(x)a3,
// a_i = (1, Ax_i, Ay_i, Az_i) Bloch components; depolarize folded as
// s^(1+nnz), s = 1-4*0.05/3.  Qubit q <-> index bit (3-q).
// ---------------------------------------------------------------------------
__global__ void qc_setup_kernel(const float* __restrict__ qw, float* __restrict__ T)
{
  __shared__ float Vr[16][16], Vi[16][16];
  __shared__ float Or[16][16], Oi[16][16];
  const int tid = threadIdx.x;
  const int r = tid >> 4, c = tid & 15;

  Vr[r][c] = (r == c) ? 1.0f : 0.0f;
  Vi[r][c] = 0.0f;
  __syncthreads();

  #pragma unroll 1
  for (int i = 0; i < 4; ++i) {
    const int cm = 8 >> i;             // control mask (qubit i)
    const int tm = 8 >> ((i + 1) & 3); // target mask (qubit (i+1)%4)
    // CNOT(control=i, target=(i+1)%4): row permutation
    {
      const int k = (r & cm) ? (r ^ tm) : r;
      const float nr = Vr[k][c], ni = Vi[k][c];
      __syncthreads();
      Vr[r][c] = nr; Vi[r][c] = ni;
      __syncthreads();
    }
    const float w  = qw[4 + i];        // qweights[1][i]
    const float ch = cosf(0.5f * w), sh = sinf(0.5f * w);
    // RY(w) on qubit i
    {
      const int m = 8 >> i;
      const int r0 = r & ~m, r1 = r | m;
      float u0, u1;
      if (r & m) { u0 = sh; u1 = ch; } else { u0 = ch; u1 = -sh; }
      const float nr = u0 * Vr[r0][c] + u1 * Vr[r1][c];
      const float ni = u0 * Vi[r0][c] + u1 * Vi[r1][c];
      __syncthreads();
      Vr[r][c] = nr; Vi[r][c] = ni;
      __syncthreads();
    }
    // RZ(w) on qubit i (diagonal)
    {
      const int m = 8 >> i;
      const float pr = ch;
      const float pi = (r & m) ? sh : -sh;
      const float vr = Vr[r][c], vi = Vi[r][c];
      Vr[r][c] = pr * vr - pi * vi;
      Vi[r][c] = pr * vi + pi * vr;
      __syncthreads();
    }
  }

  const int q  = blockIdx.x;           // one q per block
  const int zm = 8 >> q;
  // O[r][c] = sum_k conj(V[k][r]) * sign_q(k) * V[k][c]
  float orr = 0.0f, oii = 0.0f;
  for (int k = 0; k < 16; ++k) {
    const float sgn = (k & zm) ? -1.0f : 1.0f;
    const float ar = Vr[k][r], ai = -Vi[k][r];
    const float br = Vr[k][c], bi = Vi[k][c];
    orr += sgn * (ar * br - ai * bi);
    oii += sgn * (ar * bi + ai * br);
  }
  __syncthreads();
  Or[r][c] = orr; Oi[r][c] = oii;
  __syncthreads();

  // thread tid <-> Pauli string p; Tr(P O) = sum_n P[n][m(n)] * O[m(n)][n]
  const float sdep = 1.0f - 4.0f * 0.05f / 3.0f;
  const int p0 = tid >> 6, p1 = (tid >> 4) & 3, p2 = (tid >> 2) & 3, p3 = tid & 3;
  float tr = 0.0f;
  for (int n = 0; n < 16; ++n) {
    int m = n;
    float fr = 1.0f, fi = 0.0f;
    #pragma unroll
    for (int i2 = 0; i2 < 4; ++i2) {
      const int a   = (n >> (3 - i2)) & 1;
      const int pi_ = (i2 == 0) ? p0 : (i2 == 1) ? p1 : (i2 == 2) ? p2 : p3;
      if (pi_ == 1) {                    // X
        m ^= (8 >> i2);
      } else if (pi_ == 2) {             // Y
        m ^= (8 >> i2);
        const float s2  = a ? 1.0f : -1.0f;
        const float nfr = -fi * s2, nfi = fr * s2;
        fr = nfr; fi = nfi;
      } else if (pi_ == 3) {             // Z
        if (a) { fr = -fr; fi = -fi; }
      }
    }
    tr += fr * Or[m][n] - fi * Oi[m][n];
  }
  const int nnz = (p0 != 0) + (p1 != 0) + (p2 != 0) + (p3 != 0);
  float scale = 1.0f / 16.0f;
  for (int e = 0; e <= nnz; ++e) scale *= sdep;
  // p = p0*64+p1*16+p2*4+p3 = (p0*4+p1)*16 + (p2*4+p3): already M[q][j][k].
  T[q * 256 + tid] = tr * scale;
}

// ---------------------------------------------------------------------------
// Main kernel: each wave self-contained, owns RPW=32 consecutive rows.
//   A: per row: coalesced GEMV (lane=col-float4) + 6-step shfl reduce;
//      lane i keeps row i's acc (cndmask transpose, no LDS).
//   B: per-thread middle for its own row (lanes 0..31 real): tanh+LN+Bloch,
//      u=a0(x)a1, v=a2(x)a3, z[q]=sum_j u_j (M[q][j].v) with wave-uniform
//      M loads (scalarized to s_load; no VGPR table, no LDS).
//   C: per row: z broadcast via __shfl, epilogue out = x + z@Wout^T + b_out.
// No __shared__, no __syncthreads. Per-phase register sets are small, so
// nothing to rematerialize (rounds 4-7 lesson).
// ---------------------------------------------------------------------------
__global__ __launch_bounds__(256) void qlayer_main_kernel(
    const float* __restrict__ x,
    const float* __restrict__ Win,
    const float* __restrict__ b_in,
    const float* __restrict__ gamma,
    const float* __restrict__ beta,
    const float* __restrict__ qw,
    const float* __restrict__ Wout,
    const float* __restrict__ b_out,
    const float* __restrict__ M,
    float* __restrict__ out,
    int B)
{
  const int lane = threadIdx.x & 63;
  const int wg   = blockIdx.x * (blockDim.x >> 6) + (threadIdx.x >> 6);
  const int row0 = wg * RPW;
  if (row0 >= B) return;

  // ---- wave-uniform small constants (SGPR-resident) ----
  float bi[4], ga[4], be[4], cw0[4], sw0[4], cw1[4], sw1[4];
  #pragma unroll
  for (int i = 0; i < 4; ++i) {
    bi[i] = b_in[i]; ga[i] = gamma[i]; be[i] = beta[i];
    const float w0 = qw[i], w1 = qw[4 + i];
    cw0[i] = cosf(w0); sw0[i] = sinf(w0);
    cw1[i] = cosf(w1); sw1[i] = sinf(w1);
  }

  // ================= Phase A: GEMV, transpose-to-lane ======================
  float4 winf[4];
  #pragma unroll
  for (int q = 0; q < 4; ++q)
    winf[q] = *reinterpret_cast<const float4*>(&Win[q * 256 + lane * 4]);

  float am0 = 0.0f, am1 = 0.0f, am2 = 0.0f, am3 = 0.0f;  // this lane's row acc
  #pragma unroll 2
  for (int i = 0; i < RPW; ++i) {
    const float4 xv = *reinterpret_cast<const float4*>(&x[(size_t)(row0 + i) * DIM + lane * 4]);
    float a[4];
    #pragma unroll
    for (int q = 0; q < 4; ++q)
      a[q] = xv.x * winf[q].x + xv.y * winf[q].y + xv.z * winf[q].z + xv.w * winf[q].w;
    #pragma unroll
    for (int off = 1; off < 64; off <<= 1) {
      #pragma unroll
      for (int q = 0; q < 4; ++q) a[q] += __shfl_xor(a[q], off, 64);
    }
    if (lane == i) { am0 = a[0]; am1 = a[1]; am2 = a[2]; am3 = a[3]; }
  }

  // ================= Phase B: per-thread middle + contraction ==============
  // (lanes 0..RPW-1 hold real rows; others compute harmless garbage)
  float xp[4];
  {
    const float aq[4] = {am0, am1, am2, am3};
    #pragma unroll
    for (int q = 0; q < 4; ++q) {
      const float e = __expf(2.0f * (aq[q] + bi[q]));
      xp[q] = 1.0f - __fdividef(2.0f, e + 1.0f);   // tanh, inf-safe
    }
  }
  const float mu = 0.25f * (xp[0] + xp[1] + xp[2] + xp[3]);
  const float d0 = xp[0] - mu, d1 = xp[1] - mu, d2 = xp[2] - mu, d3 = xp[3] - mu;
  const float var = 0.25f * (d0 * d0 + d1 * d1 + d2 * d2 + d3 * d3);
  const float inv = rsqrtf(var + 1e-5f);

  float A0[4], A1[4], A2[4], A3[4];   // a_i = (1, Ax, Ay, Az)
  #pragma unroll
  for (int i = 0; i < 4; ++i) {
    const float ang = ((i == 0 ? d0 : i == 1 ? d1 : i == 2 ? d2 : d3) * inv) * ga[i] + be[i];
    float sn, cs;
    __sincosf(ang, &sn, &cs);
    const float ax = sn * sn;                     // RX(t) then RZ(t)
    const float ay = -sn * cs;
    const float az = cs;
    const float ay2 = ay * cw0[i] - az * sw0[i];  // RX(w0)
    const float az2 = ay * sw0[i] + az * cw0[i];
    const float Axv = ax * cw1[i] - ay2 * sw1[i]; // RZ(w1)
    const float Ayv = ax * sw1[i] + ay2 * cw1[i];
    float* dst = (i == 0) ? A0 : (i == 1) ? A1 : (i == 2) ? A2 : A3;
    dst[0] = 1.0f; dst[1] = Axv; dst[2] = Ayv; dst[3] = az2;
  }

  float u[16], v[16];
  #pragma unroll
  for (int a = 0; a < 4; ++a)
    #pragma unroll
    for (int b = 0; b < 4; ++b) {
      u[a * 4 + b] = A0[a] * A1[b];
      v[a * 4 + b] = A2[a] * A3[b];
    }

  float z0 = 0.0f, z1 = 0.0f, z2 = 0.0f, z3 = 0.0f;
  #pragma unroll 1
  for (int q = 0; q < 4; ++q) {
    float zq = 0.0f;
    #pragma unroll
    for (int j = 0; j < 16; ++j) {
      const float* Mr = &M[(q * 16 + j) * 16];   // wave-uniform -> s_load
      float w = 0.0f;
      #pragma unroll
      for (int k = 0; k < 16; ++k) w += Mr[k] * v[k];
      zq += u[j] * w;
    }
    if (q == 0) z0 = zq; else if (q == 1) z1 = zq; else if (q == 2) z2 = zq; else z3 = zq;
  }

  // ================= Phase C: epilogue =====================================
  float4 woutf[4];
  #pragma unroll
  for (int j = 0; j < 4; ++j)
    woutf[j] = *reinterpret_cast<const float4*>(&Wout[(lane * 4 + j) * 4]);
  const float4 boutf = *reinterpret_cast<const float4*>(&b_out[lane * 4]);

  #pragma unroll 2
  for (int i = 0; i < RPW; ++i) {
    const float zq0 = __shfl(z0, i, 64);
    const float zq1 = __shfl(z1, i, 64);
    const float zq2 = __shfl(z2, i, 64);
    const float zq3 = __shfl(z3, i, 64);
    const size_t base = (size_t)(row0 + i) * DIM + lane * 4;
    const float4 xv = *reinterpret_cast<const float4*>(&x[base]);
    float4 o;
    o.x = xv.x + boutf.x + zq0 * woutf[0].x + zq1 * woutf[0].y + zq2 * woutf[0].z + zq3 * woutf[0].w;
    o.y = xv.y + boutf.y + zq0 * woutf[1].x + zq1 * woutf[1].y + zq2 * woutf[1].z + zq3 * woutf[1].w;
    o.z = xv.z + boutf.z + zq0 * woutf[2].x + zq1 * woutf[2].y + zq2 * woutf[2].z + zq3 * woutf[2].w;
    o.w = xv.w + boutf.w + zq0 * woutf[3].x + zq1 * woutf[3].y + zq2 * woutf[3].z + zq3 * woutf[3].w;
    *reinterpret_cast<float4*>(&out[base]) = o;
  }
}

extern "C" void kernel_launch(void* const* d_in, const int* in_sizes, int n_in,
                              void* d_out, int out_size, void* d_ws, size_t ws_size,
                              hipStream_t stream)
{
  const float* x     = (const float*)d_in[0];
  const float* Win   = (const float*)d_in[1];
  const float* b_in  = (const float*)d_in[2];
  const float* gamma = (const float*)d_in[3];
  const float* beta  = (const float*)d_in[4];
  const float* qw    = (const float*)d_in[5];
  const float* Wout  = (const float*)d_in[6];
  const float* b_out = (const float*)d_in[7];
  float* out = (float*)d_out;
  float* T   = (float*)d_ws;            // M[4][16][16] = 4 KB
  const int B = in_sizes[0] / DIM;

  hipLaunchKernelGGL(qc_setup_kernel, dim3(4), dim3(256), 0, stream, qw, T);

  const int nwaves  = (B + RPW - 1) / RPW;          // 2048 for B=65536
  const int nblocks = (nwaves + 3) / 4;             // 4 waves/block
  hipLaunchKernelGGL(qlayer_main_kernel, dim3(nblocks), dim3(256), 0, stream,
                     x, Win, b_in, gamma, beta, qw, Wout, b_out, T, out, B);
}